// Round 6
// baseline (350.216 us; speedup 1.0000x reference)
//
#include <hip/hip_runtime.h>

// SimpleRNN: T=64, B=8, H=512, I=256, O=8, G=4, GS=64
// sign: +1 for j<=408, -1 for j>=409; exist: j<410
// chunk c: j = lane + 64c. c<=5 -> sign +1; c==7 -> sign -1 (exist=0);
// c==6 -> lane<=24: +1, lane==25: -1 (exists), lane>=26: no exist.
#define T_N 64
#define B_N 8
#define H_N 512
#define I_N 256
#define O_N 8
#define G_N 4

constexpr float DT_  = 0.02f;
constexpr float AX_  = 0.2f;    // DT/0.1
constexpr float AW_  = 0.02f;   // DT/1.0
constexpr float OMAW = 1.0f - AW_;

// Agent-scope coherent ops (sc0/sc1): bypass non-coherent L1/L2 -> LLC.
__device__ __forceinline__ void stf_agent(float* p, float v) {
    __hip_atomic_store(p, v, __ATOMIC_RELAXED, __HIP_MEMORY_SCOPE_AGENT);
}
__device__ __forceinline__ unsigned ldu_agent(const unsigned* p) {
    return __hip_atomic_load(p, __ATOMIC_RELAXED, __HIP_MEMORY_SCOPE_AGENT);
}

__device__ __forceinline__ float fast_tanh_pos(float x) {
    // x >= 0; exact at 0 and +inf. tanh(x) = 1 - 2/(e^{2x}+1)
    float ex = __expf(2.0f * x);
    return 1.0f - 2.0f / (ex + 1.0f);
}

#define SENTINEL 0xFFFFFFFFu   // hs slots memset to this each launch; tanh
                               // output in [0,1) can never alias it.

// 256 blocks x 1024 threads; wave owns one h. b = bk&7, hg = bk>>3,
// h = hg*16 + wid. Cross-block sync per step is ONE one-way agent store per
// h (the value itself, into the per-step slot hs[t][b][h]); wave 0 of each
// block polls its batch row with a per-lane done-mask and relays via LDS.
__global__ __launch_bounds__(1024) void rnn_scan(
    const float* __restrict__ x, const float* __restrict__ Rs,
    const float* __restrict__ W_x2h, const float* __restrict__ W_h2h,
    const float* __restrict__ b_h2h,
    const float* __restrict__ W_attn, const float* __restrict__ b_attn,
    const float* __restrict__ kappa, float* __restrict__ hs)
{
    __shared__ float s_out[2][H_N];         // double buffer: 1 barrier/step

    const int tid  = threadIdx.x;
    const int wid  = tid >> 6;              // 0..15
    const int lane = tid & 63;
    const int bk   = blockIdx.x;            // 0..255
    const int b    = bk & 7;
    const int hg   = bk >> 3;               // 0..31
    const int h    = (hg << 4) | wid;       // 0..511
    const int c_d  = h >> 6;                // chunk holding the diagonal
    const int dl   = h & 63;                // its lane

    // ---- loop-invariant constants (registers only) ----
    float ea[G_N][7];
#pragma unroll
    for (int g = 0; g < G_N; ++g)
#pragma unroll
        for (int c = 0; c < 7; ++c) {
            int j = lane + 64 * c;
            float w = fmaxf(W_attn[g * H_N + j], 0.0f);
            float m = (j <= 408) ? 1.0f : ((j == 409) ? -1.0f : 0.0f);
            ea[g][c] = w * m;
        }

    // x-side: ex = Wxp + wx (>=0); bwx = AW*Wxp
    float ex[4], bwx[4];
#pragma unroll
    for (int c = 0; c < 4; ++c) {
        ex[c]  = fmaxf(W_x2h[h * I_N + lane + 64 * c], 0.0f);
        bwx[c] = AW_ * ex[c];
    }
    // h2h: se = sign*(Whp+wh); bwh = AW*Whp
    float se[8], bwh[8];
#pragma unroll
    for (int c = 0; c < 8; ++c) {
        int j = lane + 64 * c;
        float s = (j <= 408) ? 1.0f : -1.0f;
        float w = fmaxf(W_h2h[h * H_N + j], 0.0f);
        se[c]  = (j == h) ? 0.0f : s * w;
        bwh[c] = AW_ * w;
    }
    const float bh = b_h2h[h];
    const float k0 = kappa[0], k1 = kappa[1], k2 = kappa[2];
    const float k3 = kappa[3], k4 = kappa[4], k5 = kappa[5];
    const float ba0 = b_attn[0], ba1 = b_attn[1], ba2 = b_attn[2], ba3 = b_attn[3];

    float st = 0.0f;

    float xv[4];
#pragma unroll
    for (int c = 0; c < 4; ++c) xv[c] = fmaxf(x[(size_t)b * I_N + lane + 64 * c], 0.0f);
    float Rcur = Rs[b];

    float outp[8];
#pragma unroll
    for (int c = 0; c < 8; ++c) outp[c] = 0.0f;   // t=0 inputs are zeros

    for (int t = 0; t < T_N; ++t) {
        // ---- 9 fused wave reductions: 4 attn logits, 4 x-dot group
        //      partials, 1 h2h dot ----
        float red[9];
#pragma unroll
        for (int g = 0; g < G_N; ++g) {
            float l = 0.0f;
#pragma unroll
            for (int c = 0; c < 7; ++c) l = fmaf(outp[c], ea[g][c], l);
            red[g] = l;
        }
#pragma unroll
        for (int c = 0; c < 4; ++c) red[4 + c] = ex[c] * xv[c];
        {
            float a = 0.0f;
#pragma unroll
            for (int c = 0; c < 8; ++c) a = fmaf(se[c], outp[c], a);
            red[8] = a;
        }
#pragma unroll
        for (int off = 32; off >= 1; off >>= 1) {
#pragma unroll
            for (int k = 0; k < 9; ++k) red[k] += __shfl_xor(red[k], off, 64);
        }

        // ---- softmax over 4 logits (bounded, no max-shift needed) ----
        float e0 = __expf(red[0] + ba0), e1 = __expf(red[1] + ba1);
        float e2 = __expf(red[2] + ba2), e3 = __expf(red[3] + ba3);
        float inv = 4.0f / (e0 + e1 + e2 + e3);     // fold *G
        float aw0 = e0 * inv, aw1 = e1 * inv, aw2 = e2 * inv, aw3 = e3 * inv;

        float total = red[4] * aw0 + red[5] * aw1 + red[6] * aw2 + red[7] * aw3
                    + red[8] + bh;

        st = st * (1.0f - AX_) + total * AX_;
        float no = fast_tanh_pos(fmaxf(st, 0.0f));

        // ---- publish: ONE one-way agent store; the value IS the signal ----
        float* hrow = hs + ((size_t)t * B_N + b) * H_N;
        if (lane == 0) stf_agent(hrow + h, no);

        if (t + 1 == T_N) break;   // final outputs handled by os kernel

        // ---- next-step input prefetch + plasticity (store in flight) ----
        const float* xr = x + ((size_t)(t + 1) * B_N + b) * I_N;
        float xvn[4];
#pragma unroll
        for (int c = 0; c < 4; ++c) xvn[c] = xr[lane + 64 * c];
        float Rn = Rs[(t + 1) * B_N + b];

        float xin[4] = { xv[0] * aw0, xv[1] * aw1, xv[2] * aw2, xv[3] * aw3 };
        float dr = DT_ * Rcur;
        float k1n = k1 * no, k2n = k2 * no, k4n = k4 * no, k5n = k5 * no;
#pragma unroll
        for (int c = 0; c < 4; ++c) {
            float hx = fmaf(k2n, xin[c], fmaf(k0, xin[c], k1n));
            ex[c] = fmaxf(fmaf(ex[c], OMAW, fmaf(dr, hx, bwx[c])), 0.0f);
        }
#pragma unroll
        for (int c = 0; c < 8; ++c) {
            float hh = fmaf(k5n, outp[c], fmaf(k3, outp[c], k4n));
            float a = se[c] * OMAW, p = fmaf(dr, hh, bwh[c]);
            float r;
            if (c <= 5)      r = fmaxf(a + p, 0.0f);
            else if (c == 7) r = fminf(a - p, 0.0f);
            else             r = (lane <= 24) ? fmaxf(a + p, 0.0f)
                                              : fminf(a - p, 0.0f);
            if (c == c_d && lane == dl) r = 0.0f;   // keep diagonal at 0
            se[c] = r;
        }

        // ---- wave 0: done-masked poll of the value row itself ----
        if (wid == 0) {
            const unsigned* urow = (const unsigned*)hrow;
            unsigned done = 0;
            float v[8];
            while (true) {
#pragma unroll
                for (int c = 0; c < 8; ++c) {
                    if (!((done >> c) & 1u)) {
                        unsigned u = ldu_agent(urow + lane + 64 * c);
                        if (u != SENTINEL) {
                            v[c] = __uint_as_float(u);
                            done |= (1u << c);
                        }
                    }
                }
                if (__all(done == 0xFFu)) break;
                __builtin_amdgcn_s_sleep(1);   // backoff: let stores land
            }
            float* sb = s_out[t & 1];
#pragma unroll
            for (int c = 0; c < 8; ++c) sb[lane + 64 * c] = v[c];
        }
        __syncthreads();   // single barrier/step (double-buffered s_out)

        const float* sb = s_out[t & 1];
#pragma unroll
        for (int c = 0; c < 8; ++c) outp[c] = sb[lane + 64 * c];
#pragma unroll
        for (int c = 0; c < 4; ++c) xv[c] = fmaxf(xvn[c], 0.0f);
        Rcur = Rn;
    }
}

// os[t,b,o] = sum_h hs[t,b,h] * relu(W_h2o[o,h]) * exist[h]
// Separate launch: kernel boundary makes all agent stores visible to plain
// cached loads. 512 blocks (t*8+b) x 512 threads (wave = o).
__global__ __launch_bounds__(512) void os_proj(
    const float* __restrict__ hs, const float* __restrict__ W_h2o,
    float* __restrict__ os)
{
    const int blk  = blockIdx.x;        // 0..511
    const int t    = blk >> 3;
    const int b    = blk & 7;
    const int o    = threadIdx.x >> 6;  // 0..7
    const int lane = threadIdx.x & 63;
    const float* hrow = hs + ((size_t)t * B_N + b) * H_N;
    float acc = 0.0f;
#pragma unroll
    for (int c = 0; c < 7; ++c) {       // c==7 has no exist
        int j = lane + 64 * c;
        float w = fmaxf(W_h2o[o * H_N + j], 0.0f);
        if (j >= 410) w = 0.0f;
        acc = fmaf(hrow[j], w, acc);
    }
#pragma unroll
    for (int off = 32; off >= 1; off >>= 1) acc += __shfl_xor(acc, off, 64);
    if (lane == 0) os[t * (B_N * O_N) + b * O_N + o] = acc;
}

extern "C" void kernel_launch(void* const* d_in, const int* in_sizes, int n_in,
                              void* d_out, int out_size, void* d_ws, size_t ws_size,
                              hipStream_t stream) {
    (void)in_sizes; (void)n_in; (void)out_size; (void)d_ws; (void)ws_size;
    const float* x      = (const float*)d_in[0];
    const float* Rs     = (const float*)d_in[1];
    const float* W_x2h  = (const float*)d_in[2];
    const float* W_h2h  = (const float*)d_in[3];
    const float* b_h2h  = (const float*)d_in[4];
    const float* W_h2o  = (const float*)d_in[5];
    const float* W_attn = (const float*)d_in[6];
    const float* b_attn = (const float*)d_in[7];
    const float* kappa  = (const float*)d_in[8];
    float* os = (float*)d_out;                       // [T][B][O]
    float* hs = (float*)d_out + T_N * B_N * O_N;     // [T][B][H]

    // sentinel-fill the per-step value slots every call (graph-legal)
    hipMemsetAsync(hs, 0xFF, (size_t)T_N * B_N * H_N * sizeof(float), stream);
    rnn_scan<<<dim3(256), dim3(1024), 0, stream>>>(
        x, Rs, W_x2h, W_h2h, b_h2h, W_attn, b_attn, kappa, hs);
    os_proj<<<dim3(512), dim3(512), 0, stream>>>(hs, W_h2o, os);
}